// Round 13
// baseline (453.201 us; speedup 1.0000x reference)
//
#include <hip/hip_runtime.h>
#include <hip/hip_bf16.h>

#define NROWS 100000
#define EDGES 600000
#define DIM 128
#define SCAN_B 391   // ceil(100000/256)

typedef unsigned short u16;
typedef __attribute__((ext_vector_type(8))) short v8s;   // 8 bf16 (4 VGPRs)
typedef __attribute__((ext_vector_type(4))) float v4f;
typedef __attribute__((ext_vector_type(2))) float f2;    // packed fp32 (v_pk_*_f32)

static __device__ __forceinline__ float bf2f(u16 u) {
  union { unsigned u; float f; } c;
  c.u = (unsigned)u << 16;
  return c.f;
}
static __device__ __forceinline__ u16 f2bf(float f) {
  union { float f; unsigned u; } c;
  c.f = f;
  unsigned r = c.u + 0x7fff + ((c.u >> 16) & 1);   // RNE
  return (u16)(r >> 16);
}
// two bf16 (packed in a dword) -> f2 {lo, hi}
static __device__ __forceinline__ f2 bfpair(unsigned v) {
  union { unsigned u[2]; f2 f; } c;
  c.u[0] = v << 16;
  c.u[1] = v & 0xffff0000u;
  return c.f;
}
static __device__ __forceinline__ long ld_idx(const void* p, long i, int is64) {
  return is64 ? (long)((const long long*)p)[i] : (long)((const int*)p)[i];
}
static __device__ __forceinline__ float ld_f(const int* flags, const void* p, long i) {
  return flags[0] ? ((const float*)p)[i] : bf2f(((const u16*)p)[i]);
}

// flags (counts; pre-zeroed by memset):
//   flags[0] = # of 0xFF-exponent u16s in table  (>0 => table is fp32)
//   flags[1] = 1 if entity is i64 (direct write, single writer)
//   flags[2] = # of nonzero high-words in edge_index head (>0 => i32; ==0 => i64)
//   flags[3] = same for edge_type
__global__ __launch_bounds__(256) void detect_kernel(
    const u16* __restrict__ table, const void* __restrict__ entity,
    const void* __restrict__ ei, const void* __restrict__ et,
    int* __restrict__ flags) {
  int gid = blockIdx.x * 256 + threadIdx.x;       // 64 blocks = 16384 threads
  const ushort4* t4 = (const ushort4*)table;      // 65536 u16 = 16384 ushort4
  ushort4 v = t4[gid];
  int cf = ((((v.x >> 7) & 0xFF) == 0xFF) ? 1 : 0) +
           ((((v.y >> 7) & 0xFF) == 0xFF) ? 1 : 0) +
           ((((v.z >> 7) & 0xFF) == 0xFF) ? 1 : 0) +
           ((((v.w >> 7) & 0xFF) == 0xFF) ? 1 : 0);
  int cei = 0, cet = 0;
  if (gid < 1024) {
    cei = (((const int*)ei)[2 * gid + 1] != 0) ? 1 : 0;
    cet = (((const int*)et)[2 * gid + 1] != 0) ? 1 : 0;
  }
  __shared__ int s_f, s_ei, s_et;
  if (threadIdx.x == 0) { s_f = 0; s_ei = 0; s_et = 0; }
  __syncthreads();
  if (cf) atomicAdd(&s_f, cf);
  if (cei) atomicAdd(&s_ei, cei);
  if (cet) atomicAdd(&s_et, cet);
  __syncthreads();
  if (threadIdx.x == 0) {
    if (s_f) atomicAdd(flags + 0, s_f);
    if (s_ei) atomicAdd(flags + 2, s_ei);
    if (s_et) atomicAdd(flags + 3, s_et);
  }
  if (gid == 0) flags[1] = (((const int*)entity)[1] == 0) ? 1 : 0;
}

// Fused prep. Wt is stored FRAGMENT-ORDERED per 128-row segment (32 KB blocks):
//   phys u16 index within seg = (k>>3)*1024 + col*8 + (k&7)
// so fgemm can stage a segment as a straight linear copy and every per-lane
// ds_read_b128 of a B-fragment is contiguous (bank-conflict-free).
// Logical row n = seg*128+col: n<512 -> basis[b=n>>7][k][c=n&127]; else root[k][n-512].
__global__ __launch_bounds__(256) void prep_kernel(
    const int* __restrict__ flags,
    const void* __restrict__ basis0, const void* __restrict__ root0, u16* __restrict__ Wt0,
    const void* __restrict__ basis1, const void* __restrict__ root1, u16* __restrict__ Wt1,
    const void* __restrict__ att0, const void* __restrict__ att1,
    float* __restrict__ attf0, float* __restrict__ attf1,
    const void* __restrict__ bias0, const void* __restrict__ bias1,
    float* __restrict__ biasf0, float* __restrict__ biasf1,
    const void* __restrict__ rel, float* __restrict__ relout) {
  int i = blockIdx.x * 256 + threadIdx.x;
  if (i < 2 * 81920) {
    const void* basis = (i < 81920) ? basis0 : basis1;
    const void* root = (i < 81920) ? root0 : root1;
    u16* Wt = (i < 81920) ? Wt0 : Wt1;
    int j = (i < 81920) ? i : i - 81920;
    int seg = j >> 14;            // 0..4 (16384 u16 per segment)
    int r = j & 16383;
    int kq = r >> 10;             // k>>3, 0..15
    int col = (r >> 3) & 127;
    int w = r & 7;
    int k = kq * 8 + w;
    int n = seg * 128 + col;
    float v;
    if (n < 512) {
      int b = n >> 7, c = n & 127;
      v = ld_f(flags, basis, (long)b * DIM * DIM + (long)k * DIM + c);
    } else {
      v = ld_f(flags, root, (long)k * DIM + (n - 512));
    }
    Wt[j] = f2bf(v);
    return;
  }
  i -= 163840;
  if (i < 64000) { relout[i] = ld_f(flags, rel, i); return; }
  i -= 64000;
  if (i < 4000) { attf0[i] = ld_f(flags, att0, i); return; }
  i -= 4000;
  if (i < 4000) { attf1[i] = ld_f(flags, att1, i); return; }
  i -= 4000;
  if (i < 128) { biasf0[i] = ld_f(flags, bias0, i); return; }
  i -= 128;
  if (i < 128) biasf1[i] = ld_f(flags, bias1, i);
}
#define PREP_THREADS (163840 + 64000 + 4000 + 4000 + 128 + 128)

// hbf bf16 (ws) = table[entity[row]]
__global__ __launch_bounds__(256) void gather_kernel(const int* __restrict__ flags,
                                                     const void* __restrict__ entity,
                                                     const void* __restrict__ table,
                                                     u16* __restrict__ hbf) {
  int gid = blockIdx.x * 256 + threadIdx.x;      // N*32 threads, 4 elems each
  int row = gid >> 5, c4 = (gid & 31) * 4;
  if (row >= NROWS) return;
  long src = ld_idx(entity, row, flags[1]);
  ushort4 o;
  if (flags[0]) {
    float4 a = *(const float4*)((const float*)table + src * DIM + c4);
    o = make_ushort4(f2bf(a.x), f2bf(a.y), f2bf(a.z), f2bf(a.w));
  } else {
    o = *(const ushort4*)((const u16*)table + src * DIM + c4);
  }
  *(ushort4*)(hbf + (long)row * DIM + c4) = o;
}

// -------- CSR build -------------------------------------------------------------
__global__ __launch_bounds__(256) void hist_kernel(const int* __restrict__ flags,
                                                   const void* __restrict__ ei,
                                                   int* __restrict__ cnt) {
  int e = blockIdx.x * 256 + threadIdx.x;
  if (e < EDGES) atomicAdd(cnt + ld_idx(ei, EDGES + e, flags[2] == 0), 1);
}

__global__ __launch_bounds__(256) void scan1_kernel(const int* __restrict__ cnt,
                                                    int* __restrict__ rowPtr,
                                                    int* __restrict__ bsum) {
  __shared__ int sh[256];
  int i = blockIdx.x * 256 + threadIdx.x;
  int v = (i < NROWS) ? cnt[i] : 0;
  sh[threadIdx.x] = v;
  __syncthreads();
#pragma unroll
  for (int off = 1; off < 256; off <<= 1) {
    int t = (threadIdx.x >= off) ? sh[threadIdx.x - off] : 0;
    __syncthreads();
    sh[threadIdx.x] += t;
    __syncthreads();
  }
  if (i < NROWS) rowPtr[i] = sh[threadIdx.x] - v;
  if (threadIdx.x == 255) bsum[blockIdx.x] = sh[255];
}

__global__ __launch_bounds__(512) void scan2_kernel(int* __restrict__ bsum,
                                                    int* __restrict__ bofs,
                                                    int* __restrict__ rowPtr) {
  __shared__ int sh[512];
  int v = (threadIdx.x < SCAN_B) ? bsum[threadIdx.x] : 0;
  sh[threadIdx.x] = v;
  __syncthreads();
#pragma unroll
  for (int off = 1; off < 512; off <<= 1) {
    int t = (threadIdx.x >= off) ? sh[threadIdx.x - off] : 0;
    __syncthreads();
    sh[threadIdx.x] += t;
    __syncthreads();
  }
  if (threadIdx.x < SCAN_B) bofs[threadIdx.x] = sh[threadIdx.x] - v;
  if (threadIdx.x == 511) rowPtr[NROWS] = sh[511];
}

__global__ __launch_bounds__(256) void scan3_kernel(int* __restrict__ rowPtr,
                                                    const int* __restrict__ bofs,
                                                    int* __restrict__ cursor) {
  int i = blockIdx.x * 256 + threadIdx.x;
  if (i >= NROWS) return;
  int r = rowPtr[i] + bofs[blockIdx.x];
  rowPtr[i] = r;
  cursor[i] = r;
}

// One 8B store per edge: {src | t<<17, norm bits}.
__global__ __launch_bounds__(256) void scatter_kernel(const int* __restrict__ flags,
                                                      const void* __restrict__ ei,
                                                      const void* __restrict__ et,
                                                      const void* __restrict__ enorm,
                                                      int* __restrict__ cursor,
                                                      int2* __restrict__ csr8) {
  int e = blockIdx.x * 256 + threadIdx.x;
  if (e >= EDGES) return;
  int is64e = (flags[2] == 0), is64t = (flags[3] == 0);
  int dst = (int)ld_idx(ei, EDGES + e, is64e);
  int src = (int)ld_idx(ei, e, is64e);
  int t = (int)ld_idx(et, e, is64t);
  float nrm = ld_f(flags, enorm, e);
  int pos = atomicAdd(cursor + dst, 1);
  int2 v;
  v.x = src | (t << 17);
  v.y = __float_as_int(nrm);
  csr8[pos] = v;
}

// -------- input-space aggregation: Z_b[dst] = (1/deg) * sum_e att[t][b]*norm*h[src]
// One wave per dst node; lane covers cols {2*lane, 2*lane+1} as a PACKED float2.
// Edge loop unrolled x4 (r11-verified best). Z stores are NON-TEMPORAL: the
// 100 MB write-once stream was evicting the 25.6 MB hin from L3 (r12 counters:
// zagg FETCH=74 MB >> hin size); nt keeps hin resident so gathers hit cache.
__global__ __launch_bounds__(256) void zagg_kernel(
    const int* __restrict__ rowPtr, const int2* __restrict__ csr8,
    const float* __restrict__ att_f,
    const u16* __restrict__ hin, u16* __restrict__ Z, int c0, int c1) {
  int wid = (blockIdx.x * 256 + threadIdx.x) >> 6;
  int node = c0 + wid;
  if (node >= c1) return;
  int lane = threadIdx.x & 63, d = lane * 2;
  int beg = rowPtr[node], end = rowPtr[node + 1];
  const float4* att4 = (const float4*)att_f;
  f2 z0 = {0.f, 0.f}, z1 = {0.f, 0.f}, z2 = {0.f, 0.f}, z3 = {0.f, 0.f};
  int e = beg;
  for (; e + 3 < end; e += 4) {
    int2 p0 = csr8[e], p1 = csr8[e + 1], p2 = csr8[e + 2], p3 = csr8[e + 3];
    unsigned v0 = *(const unsigned*)(hin + (long)(p0.x & 0x1FFFF) * DIM + d);
    unsigned v1 = *(const unsigned*)(hin + (long)(p1.x & 0x1FFFF) * DIM + d);
    unsigned v2 = *(const unsigned*)(hin + (long)(p2.x & 0x1FFFF) * DIM + d);
    unsigned v3 = *(const unsigned*)(hin + (long)(p3.x & 0x1FFFF) * DIM + d);
    float4 a0 = att4[p0.x >> 17];
    float4 a1 = att4[p1.x >> 17];
    float4 a2 = att4[p2.x >> 17];
    float4 a3 = att4[p3.x >> 17];
    float n0 = __int_as_float(p0.y), n1 = __int_as_float(p1.y);
    float n2 = __int_as_float(p2.y), n3 = __int_as_float(p3.y);
    f2 y0 = bfpair(v0) * (f2){n0, n0};
    f2 y1 = bfpair(v1) * (f2){n1, n1};
    f2 y2 = bfpair(v2) * (f2){n2, n2};
    f2 y3 = bfpair(v3) * (f2){n3, n3};
    z0 = (f2){a0.x, a0.x} * y0 + z0;
    z1 = (f2){a0.y, a0.y} * y0 + z1;
    z2 = (f2){a0.z, a0.z} * y0 + z2;
    z3 = (f2){a0.w, a0.w} * y0 + z3;
    z0 = (f2){a1.x, a1.x} * y1 + z0;
    z1 = (f2){a1.y, a1.y} * y1 + z1;
    z2 = (f2){a1.z, a1.z} * y1 + z2;
    z3 = (f2){a1.w, a1.w} * y1 + z3;
    z0 = (f2){a2.x, a2.x} * y2 + z0;
    z1 = (f2){a2.y, a2.y} * y2 + z1;
    z2 = (f2){a2.z, a2.z} * y2 + z2;
    z3 = (f2){a2.w, a2.w} * y2 + z3;
    z0 = (f2){a3.x, a3.x} * y3 + z0;
    z1 = (f2){a3.y, a3.y} * y3 + z1;
    z2 = (f2){a3.z, a3.z} * y3 + z2;
    z3 = (f2){a3.w, a3.w} * y3 + z3;
  }
  for (; e < end; ++e) {
    int2 p0 = csr8[e];
    unsigned v0 = *(const unsigned*)(hin + (long)(p0.x & 0x1FFFF) * DIM + d);
    float4 a0 = att4[p0.x >> 17];
    float n0 = __int_as_float(p0.y);
    f2 y0 = bfpair(v0) * (f2){n0, n0};
    z0 = (f2){a0.x, a0.x} * y0 + z0;
    z1 = (f2){a0.y, a0.y} * y0 + z1;
    z2 = (f2){a0.z, a0.z} * y0 + z2;
    z3 = (f2){a0.w, a0.w} * y0 + z3;
  }
  float invd = 1.0f / fmaxf((float)(end - beg), 1.0f);
  f2 iv = {invd, invd};
  z0 *= iv; z1 *= iv; z2 *= iv; z3 *= iv;
  unsigned* zp = (unsigned*)(Z + (long)(node - c0) * 512) + lane;
  __builtin_nontemporal_store((unsigned)f2bf(z0[0]) | ((unsigned)f2bf(z0[1]) << 16), zp);
  __builtin_nontemporal_store((unsigned)f2bf(z1[0]) | ((unsigned)f2bf(z1[1]) << 16), zp + 64);
  __builtin_nontemporal_store((unsigned)f2bf(z2[0]) | ((unsigned)f2bf(z2[1]) << 16), zp + 128);
  __builtin_nontemporal_store((unsigned)f2bf(z3[0]) | ((unsigned)f2bf(z3[1]) << 16), zp + 192);
}

// -------- fused GEMM over K=640: out = [Z0|Z1|Z2|Z3|h] @ Wt^T + bias ------------
// 512 threads, 64 rows/block, 8 waves = 4 row-frags x 2 col-halves.
// Wt is fragment-ordered (see prep): staging = straight 32KB linear copy; each
// B-fragment ds_read_b128 is contiguous -> no bank conflicts. 32KB LDS ->
// 4 blocks/CU x 8 waves = 32 waves/CU (full occupancy cap).
// Z A-fragments use NON-TEMPORAL loads (read-exactly-once stream; keeps Wt/hin
// resident in L2). Segments 0..3: A from Z, segment 4: A from hin (root term).
// finalMode 1: hout = bf16(relu(out)) | 2: outp = fp32 out
__global__ __launch_bounds__(512) void fgemm_kernel(
    const u16* __restrict__ Z, const u16* __restrict__ hin,
    const u16* __restrict__ Wt, const float* __restrict__ bias,
    int c0, int c1, int finalMode,
    u16* __restrict__ hout, float* __restrict__ outp) {
  __shared__ u16 Wl[16384];   // 32 KB, fragment layout [k>>3][col][k&7]
  int tid = threadIdx.x;
  int wv = tid >> 6, lane = tid & 63;
  int rt = wv >> 1, ch = wv & 1;          // row-frag 0..3, col-half 0..1
  int quad = lane >> 4, l16 = lane & 15;
  long lrow = (long)blockIdx.x * 64 + rt * 16 + l16;   // chunk-local
  long arow = c0 + lrow;
  bool rv = arow < c1;

  v4f av[4];
#pragma unroll
  for (int nt = 0; nt < 4; ++nt) av[nt] = (v4f){0.f, 0.f, 0.f, 0.f};

  for (int seg = 0; seg < 5; ++seg) {
    if (seg) __syncthreads();            // protect Wl before overwrite
#pragma unroll
    for (int it = 0; it < 4; ++it) {
      int o = (tid + it * 512) * 8;
      *(int4*)&Wl[o] = *(const int4*)&Wt[(long)seg * 16384 + o];
    }
    __syncthreads();
    const u16* abase = (seg < 4) ? Z + lrow * 512 + seg * 128
                                 : hin + arow * 128;
#pragma unroll
    for (int ks = 0; ks < 4; ++ks) {
      v8s a = {0, 0, 0, 0, 0, 0, 0, 0};
      if (rv) {
        if (seg < 4) a = __builtin_nontemporal_load((const v8s*)&abase[ks * 32 + quad * 8]);
        else         a = *(const v8s*)&abase[ks * 32 + quad * 8];
      }
      const u16* wb = &Wl[(ks * 4 + quad) * 1024 + ch * 512];
#pragma unroll
      for (int nt = 0; nt < 4; ++nt) {
        v8s b = *(const v8s*)&wb[(nt * 16 + l16) * 8];
        av[nt] = __builtin_amdgcn_mfma_f32_16x16x32_bf16(a, b, av[nt], 0, 0, 0);
      }
    }
  }

  long orow0 = c0 + (long)blockIdx.x * 64 + rt * 16 + quad * 4;
#pragma unroll
  for (int nt = 0; nt < 4; ++nt) {
    int col = ch * 64 + nt * 16 + l16;
    float bv = bias[col];
#pragma unroll
    for (int r = 0; r < 4; ++r) {
      long row = orow0 + r;
      if (row >= c1) continue;
      float v = av[nt][r] + bv;
      if (finalMode == 1) hout[row * DIM + col] = f2bf(fmaxf(v, 0.f));
      else                outp[row * DIM + col] = v;
    }
  }
}

static size_t alignup(size_t x) { return (x + 255) & ~(size_t)255; }

extern "C" void kernel_launch(void* const* d_in, const int* in_sizes, int n_in,
                              void* d_out, int out_size, void* d_ws, size_t ws_size,
                              hipStream_t stream) {
  static const long exp_sz[15] = {100000, 1200000, 600000, 600000, 250000,
                                  12800000, 64000, 65536, 4000, 16384, 128,
                                  65536, 4000, 16384, 128};
  int map[15];
  bool posOK = (n_in >= 15);
  for (int i = 0; posOK && i < 15; ++i) posOK = (in_sizes[i] == exp_sz[i]);
  if (posOK) {
    for (int i = 0; i < 15; ++i) map[i] = i;
  } else {
    bool used[64] = {};
    for (int i = 0; i < 15; ++i) {
      map[i] = -1;
      for (int j = 0; j < n_in && j < 64; ++j)
        if (!used[j] && in_sizes[j] == exp_sz[i]) { map[i] = j; used[j] = true; break; }
      if (map[i] < 0) map[i] = (i < n_in) ? i : 0;
    }
  }
  const void* entity = d_in[map[0]];
  const void* edge_index = d_in[map[1]];
  const void* edge_type = d_in[map[2]];
  const void* edge_norm = d_in[map[3]];
  const void* table = d_in[map[5]];
  const void* rel_emb = d_in[map[6]];
  const void* basis[2] = {d_in[map[7]], d_in[map[11]]};
  const void* att[2] = {d_in[map[8]], d_in[map[12]]};
  const void* root[2] = {d_in[map[9]], d_in[map[13]]};
  const void* bias[2] = {d_in[map[10]], d_in[map[14]]};

  // ---- fixed ws layout ----
  char* ws = (char*)d_ws;
  size_t off = 0;
  auto grab = [&](size_t bytes) { size_t o = off; off = alignup(off + bytes); return o; };
  int* flags = (int*)(ws + grab(16));
  float* att_f[2] = {(float*)(ws + grab(4000 * 4)), (float*)(ws + grab(4000 * 4))};
  float* bias_f[2] = {(float*)(ws + grab(DIM * 4)), (float*)(ws + grab(DIM * 4))};
  u16* Wt[2] = {(u16*)(ws + grab(640 * 128 * 2)), (u16*)(ws + grab(640 * 128 * 2))};
  int* cnt = (int*)(ws + grab((size_t)NROWS * 4));
  int* cursor = (int*)(ws + grab((size_t)NROWS * 4));
  int* rowPtr = (int*)(ws + grab((size_t)(NROWS + 1) * 4));
  int* bsum = (int*)(ws + grab((size_t)SCAN_B * 4));
  int* bofs = (int*)(ws + grab((size_t)SCAN_B * 4));
  int2* csr8 = (int2*)(ws + grab((size_t)EDGES * 8));
  u16* hbf = (u16*)(ws + grab((size_t)NROWS * DIM * 2));
  u16* hbf2 = (u16*)(ws + grab((size_t)NROWS * DIM * 2));
  size_t fixedB = off;

  // ---- pick node-chunk count NC (Z fits L3 at NC=1; prefer fewest dispatches) ----
  static const int ncOrd[5] = {1, 2, 4, 8, 16};
  int NC = 16;
  for (int i = 0; i < 5; ++i) {
    int nc = ncOrd[i];
    size_t r = (NROWS + nc - 1) / nc;
    if (fixedB + alignup(r * 512 * 2) <= ws_size) { NC = nc; break; }
  }
  const int rpc = (NROWS + NC - 1) / NC;
  u16* Z = (u16*)(ws + grab((size_t)rpc * 512 * 2));

  // ---- prep ----
  hipMemsetAsync(flags, 0, 16, stream);
  hipMemsetAsync(cnt, 0, (size_t)NROWS * 4, stream);
  detect_kernel<<<64, 256, 0, stream>>>((const u16*)table, entity, edge_index,
                                        edge_type, flags);
  prep_kernel<<<(PREP_THREADS + 255) / 256, 256, 0, stream>>>(
      flags, basis[0], root[0], Wt[0], basis[1], root[1], Wt[1],
      att[0], att[1], att_f[0], att_f[1],
      bias[0], bias[1], bias_f[0], bias_f[1],
      rel_emb, (float*)d_out + (size_t)NROWS * DIM);
  gather_kernel<<<(NROWS * 32 + 255) / 256, 256, 0, stream>>>(flags, entity, table, hbf);
  hist_kernel<<<(EDGES + 255) / 256, 256, 0, stream>>>(flags, edge_index, cnt);
  scan1_kernel<<<SCAN_B, 256, 0, stream>>>(cnt, rowPtr, bsum);
  scan2_kernel<<<1, 512, 0, stream>>>(bsum, bofs, rowPtr);
  scan3_kernel<<<SCAN_B, 256, 0, stream>>>(rowPtr, bofs, cursor);
  scatter_kernel<<<(EDGES + 255) / 256, 256, 0, stream>>>(
      flags, edge_index, edge_type, edge_norm, cursor, csr8);

  // ---- two RGCN layers: aggregate in input space, then one fused K=640 GEMM ----
  const u16* hin = hbf;
  for (int l = 0; l < 2; ++l) {
    for (int c = 0; c < NC; ++c) {
      int c0 = c * rpc, c1 = (c0 + rpc < NROWS) ? c0 + rpc : NROWS;
      int rc = c1 - c0;
      zagg_kernel<<<(rc * 64 + 255) / 256, 256, 0, stream>>>(
          rowPtr, csr8, att_f[l], hin, Z, c0, c1);
      fgemm_kernel<<<(rc + 63) / 64, 512, 0, stream>>>(
          Z, hin, Wt[l], bias_f[l], c0, c1, (l == 0) ? 1 : 2, hbf2, (float*)d_out);
    }
    hin = hbf2;
  }
}

// Round 14
// 418.236 us; speedup vs baseline: 1.0836x; 1.0836x over previous
//
#include <hip/hip_runtime.h>
#include <hip/hip_bf16.h>

#define NROWS 100000
#define EDGES 600000
#define DIM 128
#define SCAN_B 391   // ceil(100000/256)

typedef unsigned short u16;
typedef __attribute__((ext_vector_type(8))) short v8s;   // 8 bf16 (4 VGPRs)
typedef __attribute__((ext_vector_type(4))) float v4f;
typedef __attribute__((ext_vector_type(2))) float f2;    // packed fp32 (v_pk_*_f32)

static __device__ __forceinline__ float bf2f(u16 u) {
  union { unsigned u; float f; } c;
  c.u = (unsigned)u << 16;
  return c.f;
}
static __device__ __forceinline__ u16 f2bf(float f) {
  union { float f; unsigned u; } c;
  c.f = f;
  unsigned r = c.u + 0x7fff + ((c.u >> 16) & 1);   // RNE
  return (u16)(r >> 16);
}
// two bf16 (packed in a dword) -> f2 {lo, hi}
static __device__ __forceinline__ f2 bfpair(unsigned v) {
  union { unsigned u[2]; f2 f; } c;
  c.u[0] = v << 16;
  c.u[1] = v & 0xffff0000u;
  return c.f;
}
static __device__ __forceinline__ long ld_idx(const void* p, long i, int is64) {
  return is64 ? (long)((const long long*)p)[i] : (long)((const int*)p)[i];
}
static __device__ __forceinline__ float ld_f(const int* flags, const void* p, long i) {
  return flags[0] ? ((const float*)p)[i] : bf2f(((const u16*)p)[i]);
}

// flags (counts; pre-zeroed by memset):
//   flags[0] = # of 0xFF-exponent u16s in table  (>0 => table is fp32)
//   flags[1] = 1 if entity is i64 (direct write, single writer)
//   flags[2] = # of nonzero high-words in edge_index head (>0 => i32; ==0 => i64)
//   flags[3] = same for edge_type
__global__ __launch_bounds__(256) void detect_kernel(
    const u16* __restrict__ table, const void* __restrict__ entity,
    const void* __restrict__ ei, const void* __restrict__ et,
    int* __restrict__ flags) {
  int gid = blockIdx.x * 256 + threadIdx.x;       // 64 blocks = 16384 threads
  const ushort4* t4 = (const ushort4*)table;      // 65536 u16 = 16384 ushort4
  ushort4 v = t4[gid];
  int cf = ((((v.x >> 7) & 0xFF) == 0xFF) ? 1 : 0) +
           ((((v.y >> 7) & 0xFF) == 0xFF) ? 1 : 0) +
           ((((v.z >> 7) & 0xFF) == 0xFF) ? 1 : 0) +
           ((((v.w >> 7) & 0xFF) == 0xFF) ? 1 : 0);
  int cei = 0, cet = 0;
  if (gid < 1024) {
    cei = (((const int*)ei)[2 * gid + 1] != 0) ? 1 : 0;
    cet = (((const int*)et)[2 * gid + 1] != 0) ? 1 : 0;
  }
  __shared__ int s_f, s_ei, s_et;
  if (threadIdx.x == 0) { s_f = 0; s_ei = 0; s_et = 0; }
  __syncthreads();
  if (cf) atomicAdd(&s_f, cf);
  if (cei) atomicAdd(&s_ei, cei);
  if (cet) atomicAdd(&s_et, cet);
  __syncthreads();
  if (threadIdx.x == 0) {
    if (s_f) atomicAdd(flags + 0, s_f);
    if (s_ei) atomicAdd(flags + 2, s_ei);
    if (s_et) atomicAdd(flags + 3, s_et);
  }
  if (gid == 0) flags[1] = (((const int*)entity)[1] == 0) ? 1 : 0;
}

// -------- fused prep | gather | hist (all depend only on flags; disjoint outputs,
// complementary bottlenecks: streaming / gather-latency / atomic line-fill) ------
// Wt stored FRAGMENT-ORDERED per 128-row segment (32 KB blocks):
//   phys u16 index within seg = (k>>3)*1024 + col*8 + (k&7)
// Logical row n = seg*128+col: n<512 -> basis[b=n>>7][k][c=n&127]; else root[k][n-512].
#define PREP_THREADS (163840 + 64000 + 4000 + 4000 + 128 + 128)
#define PB ((PREP_THREADS + 255) / 256)        // 923
#define GB ((NROWS * 32 + 255) / 256)          // 12500
#define HB ((EDGES + 255) / 256)               // 2344
__global__ __launch_bounds__(256) void pgh_kernel(
    const int* __restrict__ flags,
    const void* __restrict__ basis0, const void* __restrict__ root0, u16* __restrict__ Wt0,
    const void* __restrict__ basis1, const void* __restrict__ root1, u16* __restrict__ Wt1,
    const void* __restrict__ att0, const void* __restrict__ att1,
    float* __restrict__ attf0, float* __restrict__ attf1,
    const void* __restrict__ bias0, const void* __restrict__ bias1,
    float* __restrict__ biasf0, float* __restrict__ biasf1,
    const void* __restrict__ rel, float* __restrict__ relout,
    const void* __restrict__ entity, const void* __restrict__ table,
    u16* __restrict__ hbf,
    const void* __restrict__ ei, int* __restrict__ cnt) {
  int b = blockIdx.x;
  if (b < PB) {
    // ---- prep ----
    int i = b * 256 + threadIdx.x;
    if (i < 2 * 81920) {
      const void* basis = (i < 81920) ? basis0 : basis1;
      const void* root = (i < 81920) ? root0 : root1;
      u16* Wt = (i < 81920) ? Wt0 : Wt1;
      int j = (i < 81920) ? i : i - 81920;
      int seg = j >> 14;            // 0..4 (16384 u16 per segment)
      int r = j & 16383;
      int kq = r >> 10;             // k>>3, 0..15
      int col = (r >> 3) & 127;
      int w = r & 7;
      int k = kq * 8 + w;
      int n = seg * 128 + col;
      float v;
      if (n < 512) {
        int bb = n >> 7, c = n & 127;
        v = ld_f(flags, basis, (long)bb * DIM * DIM + (long)k * DIM + c);
      } else {
        v = ld_f(flags, root, (long)k * DIM + (n - 512));
      }
      Wt[j] = f2bf(v);
      return;
    }
    i -= 163840;
    if (i < 64000) { relout[i] = ld_f(flags, rel, i); return; }
    i -= 64000;
    if (i < 4000) { attf0[i] = ld_f(flags, att0, i); return; }
    i -= 4000;
    if (i < 4000) { attf1[i] = ld_f(flags, att1, i); return; }
    i -= 4000;
    if (i < 128) { biasf0[i] = ld_f(flags, bias0, i); return; }
    i -= 128;
    if (i < 128) biasf1[i] = ld_f(flags, bias1, i);
    return;
  }
  if (b < PB + GB) {
    // ---- gather: hbf = bf16(table[entity[row]]) ----
    int gid = (b - PB) * 256 + threadIdx.x;      // N*32 threads, 4 elems each
    int row = gid >> 5, c4 = (gid & 31) * 4;
    if (row >= NROWS) return;
    long src = ld_idx(entity, row, flags[1]);
    ushort4 o;
    if (flags[0]) {
      float4 a = *(const float4*)((const float*)table + src * DIM + c4);
      o = make_ushort4(f2bf(a.x), f2bf(a.y), f2bf(a.z), f2bf(a.w));
    } else {
      o = *(const ushort4*)((const u16*)table + src * DIM + c4);
    }
    *(ushort4*)(hbf + (long)row * DIM + c4) = o;
    return;
  }
  // ---- hist ----
  int e = (b - PB - GB) * 256 + threadIdx.x;
  if (e < EDGES) atomicAdd(cnt + ld_idx(ei, EDGES + e, flags[2] == 0), 1);
}

// -------- CSR build -------------------------------------------------------------
__global__ __launch_bounds__(256) void scan1_kernel(const int* __restrict__ cnt,
                                                    int* __restrict__ rowPtr,
                                                    int* __restrict__ bsum) {
  __shared__ int sh[256];
  int i = blockIdx.x * 256 + threadIdx.x;
  int v = (i < NROWS) ? cnt[i] : 0;
  sh[threadIdx.x] = v;
  __syncthreads();
#pragma unroll
  for (int off = 1; off < 256; off <<= 1) {
    int t = (threadIdx.x >= off) ? sh[threadIdx.x - off] : 0;
    __syncthreads();
    sh[threadIdx.x] += t;
    __syncthreads();
  }
  if (i < NROWS) rowPtr[i] = sh[threadIdx.x] - v;
  if (threadIdx.x == 255) bsum[blockIdx.x] = sh[255];
}

__global__ __launch_bounds__(512) void scan2_kernel(int* __restrict__ bsum,
                                                    int* __restrict__ bofs,
                                                    int* __restrict__ rowPtr) {
  __shared__ int sh[512];
  int v = (threadIdx.x < SCAN_B) ? bsum[threadIdx.x] : 0;
  sh[threadIdx.x] = v;
  __syncthreads();
#pragma unroll
  for (int off = 1; off < 512; off <<= 1) {
    int t = (threadIdx.x >= off) ? sh[threadIdx.x - off] : 0;
    __syncthreads();
    sh[threadIdx.x] += t;
    __syncthreads();
  }
  if (threadIdx.x < SCAN_B) bofs[threadIdx.x] = sh[threadIdx.x] - v;
  if (threadIdx.x == 511) rowPtr[NROWS] = sh[511];
}

__global__ __launch_bounds__(256) void scan3_kernel(int* __restrict__ rowPtr,
                                                    const int* __restrict__ bofs,
                                                    int* __restrict__ cursor) {
  int i = blockIdx.x * 256 + threadIdx.x;
  if (i >= NROWS) return;
  int r = rowPtr[i] + bofs[blockIdx.x];
  rowPtr[i] = r;
  cursor[i] = r;
}

// One 8B store per edge: {src | t<<17, norm bits}.
__global__ __launch_bounds__(256) void scatter_kernel(const int* __restrict__ flags,
                                                      const void* __restrict__ ei,
                                                      const void* __restrict__ et,
                                                      const void* __restrict__ enorm,
                                                      int* __restrict__ cursor,
                                                      int2* __restrict__ csr8) {
  int e = blockIdx.x * 256 + threadIdx.x;
  if (e >= EDGES) return;
  int is64e = (flags[2] == 0), is64t = (flags[3] == 0);
  int dst = (int)ld_idx(ei, EDGES + e, is64e);
  int src = (int)ld_idx(ei, e, is64e);
  int t = (int)ld_idx(et, e, is64t);
  float nrm = ld_f(flags, enorm, e);
  int pos = atomicAdd(cursor + dst, 1);
  int2 v;
  v.x = src | (t << 17);
  v.y = __float_as_int(nrm);
  csr8[pos] = v;
}

// -------- input-space aggregation: Z_b[dst] = (1/deg) * sum_e att[t][b]*norm*h[src]
// One wave per dst node; lane covers cols {2*lane, 2*lane+1} as a PACKED float2.
// Edge loop unrolled x4 (r11-verified best). Normal stores (nt regressed in r13).
__global__ __launch_bounds__(256) void zagg_kernel(
    const int* __restrict__ rowPtr, const int2* __restrict__ csr8,
    const float* __restrict__ att_f,
    const u16* __restrict__ hin, u16* __restrict__ Z, int c0, int c1) {
  int wid = (blockIdx.x * 256 + threadIdx.x) >> 6;
  int node = c0 + wid;
  if (node >= c1) return;
  int lane = threadIdx.x & 63, d = lane * 2;
  int beg = rowPtr[node], end = rowPtr[node + 1];
  const float4* att4 = (const float4*)att_f;
  f2 z0 = {0.f, 0.f}, z1 = {0.f, 0.f}, z2 = {0.f, 0.f}, z3 = {0.f, 0.f};
  int e = beg;
  for (; e + 3 < end; e += 4) {
    int2 p0 = csr8[e], p1 = csr8[e + 1], p2 = csr8[e + 2], p3 = csr8[e + 3];
    unsigned v0 = *(const unsigned*)(hin + (long)(p0.x & 0x1FFFF) * DIM + d);
    unsigned v1 = *(const unsigned*)(hin + (long)(p1.x & 0x1FFFF) * DIM + d);
    unsigned v2 = *(const unsigned*)(hin + (long)(p2.x & 0x1FFFF) * DIM + d);
    unsigned v3 = *(const unsigned*)(hin + (long)(p3.x & 0x1FFFF) * DIM + d);
    float4 a0 = att4[p0.x >> 17];
    float4 a1 = att4[p1.x >> 17];
    float4 a2 = att4[p2.x >> 17];
    float4 a3 = att4[p3.x >> 17];
    float n0 = __int_as_float(p0.y), n1 = __int_as_float(p1.y);
    float n2 = __int_as_float(p2.y), n3 = __int_as_float(p3.y);
    f2 y0 = bfpair(v0) * (f2){n0, n0};
    f2 y1 = bfpair(v1) * (f2){n1, n1};
    f2 y2 = bfpair(v2) * (f2){n2, n2};
    f2 y3 = bfpair(v3) * (f2){n3, n3};
    z0 = (f2){a0.x, a0.x} * y0 + z0;
    z1 = (f2){a0.y, a0.y} * y0 + z1;
    z2 = (f2){a0.z, a0.z} * y0 + z2;
    z3 = (f2){a0.w, a0.w} * y0 + z3;
    z0 = (f2){a1.x, a1.x} * y1 + z0;
    z1 = (f2){a1.y, a1.y} * y1 + z1;
    z2 = (f2){a1.z, a1.z} * y1 + z2;
    z3 = (f2){a1.w, a1.w} * y1 + z3;
    z0 = (f2){a2.x, a2.x} * y2 + z0;
    z1 = (f2){a2.y, a2.y} * y2 + z1;
    z2 = (f2){a2.z, a2.z} * y2 + z2;
    z3 = (f2){a2.w, a2.w} * y2 + z3;
    z0 = (f2){a3.x, a3.x} * y3 + z0;
    z1 = (f2){a3.y, a3.y} * y3 + z1;
    z2 = (f2){a3.z, a3.z} * y3 + z2;
    z3 = (f2){a3.w, a3.w} * y3 + z3;
  }
  for (; e < end; ++e) {
    int2 p0 = csr8[e];
    unsigned v0 = *(const unsigned*)(hin + (long)(p0.x & 0x1FFFF) * DIM + d);
    float4 a0 = att4[p0.x >> 17];
    float n0 = __int_as_float(p0.y);
    f2 y0 = bfpair(v0) * (f2){n0, n0};
    z0 = (f2){a0.x, a0.x} * y0 + z0;
    z1 = (f2){a0.y, a0.y} * y0 + z1;
    z2 = (f2){a0.z, a0.z} * y0 + z2;
    z3 = (f2){a0.w, a0.w} * y0 + z3;
  }
  float invd = 1.0f / fmaxf((float)(end - beg), 1.0f);
  f2 iv = {invd, invd};
  z0 *= iv; z1 *= iv; z2 *= iv; z3 *= iv;
  unsigned* zp = (unsigned*)(Z + (long)(node - c0) * 512) + lane;
  zp[0]   = (unsigned)f2bf(z0[0]) | ((unsigned)f2bf(z0[1]) << 16);
  zp[64]  = (unsigned)f2bf(z1[0]) | ((unsigned)f2bf(z1[1]) << 16);
  zp[128] = (unsigned)f2bf(z2[0]) | ((unsigned)f2bf(z2[1]) << 16);
  zp[192] = (unsigned)f2bf(z3[0]) | ((unsigned)f2bf(z3[1]) << 16);
}

// -------- fused GEMM over K=640: out = [Z0|Z1|Z2|Z3|h] @ Wt^T + bias ------------
// 512 threads, 64 rows/block, 8 waves = 4 row-frags x 2 col-halves.
// Wt fragment-ordered (see prep): staging = straight 32KB linear copy; each
// B-fragment ds_read_b128 is contiguous -> no bank conflicts (r12-verified).
// Segments 0..3: A from Z (chunk-local), segment 4: A from hin (root term).
// finalMode 1: hout = bf16(relu(out)) | 2: outp = fp32 out
__global__ __launch_bounds__(512) void fgemm_kernel(
    const u16* __restrict__ Z, const u16* __restrict__ hin,
    const u16* __restrict__ Wt, const float* __restrict__ bias,
    int c0, int c1, int finalMode,
    u16* __restrict__ hout, float* __restrict__ outp) {
  __shared__ u16 Wl[16384];   // 32 KB, fragment layout [k>>3][col][k&7]
  int tid = threadIdx.x;
  int wv = tid >> 6, lane = tid & 63;
  int rt = wv >> 1, ch = wv & 1;          // row-frag 0..3, col-half 0..1
  int quad = lane >> 4, l16 = lane & 15;
  long lrow = (long)blockIdx.x * 64 + rt * 16 + l16;   // chunk-local
  long arow = c0 + lrow;
  bool rv = arow < c1;

  v4f av[4];
#pragma unroll
  for (int nt = 0; nt < 4; ++nt) av[nt] = (v4f){0.f, 0.f, 0.f, 0.f};

  for (int seg = 0; seg < 5; ++seg) {
    if (seg) __syncthreads();            // protect Wl before overwrite
#pragma unroll
    for (int it = 0; it < 4; ++it) {
      int o = (tid + it * 512) * 8;
      *(int4*)&Wl[o] = *(const int4*)&Wt[(long)seg * 16384 + o];
    }
    __syncthreads();
    const u16* abase = (seg < 4) ? Z + lrow * 512 + seg * 128
                                 : hin + arow * 128;
#pragma unroll
    for (int ks = 0; ks < 4; ++ks) {
      v8s a = {0, 0, 0, 0, 0, 0, 0, 0};
      if (rv) a = *(const v8s*)&abase[ks * 32 + quad * 8];
      const u16* wb = &Wl[(ks * 4 + quad) * 1024 + ch * 512];
#pragma unroll
      for (int nt = 0; nt < 4; ++nt) {
        v8s b = *(const v8s*)&wb[(nt * 16 + l16) * 8];
        av[nt] = __builtin_amdgcn_mfma_f32_16x16x32_bf16(a, b, av[nt], 0, 0, 0);
      }
    }
  }

  long orow0 = c0 + (long)blockIdx.x * 64 + rt * 16 + quad * 4;
#pragma unroll
  for (int nt = 0; nt < 4; ++nt) {
    int col = ch * 64 + nt * 16 + l16;
    float bv = bias[col];
#pragma unroll
    for (int r = 0; r < 4; ++r) {
      long row = orow0 + r;
      if (row >= c1) continue;
      float v = av[nt][r] + bv;
      if (finalMode == 1) hout[row * DIM + col] = f2bf(fmaxf(v, 0.f));
      else                outp[row * DIM + col] = v;
    }
  }
}

static size_t alignup(size_t x) { return (x + 255) & ~(size_t)255; }

extern "C" void kernel_launch(void* const* d_in, const int* in_sizes, int n_in,
                              void* d_out, int out_size, void* d_ws, size_t ws_size,
                              hipStream_t stream) {
  static const long exp_sz[15] = {100000, 1200000, 600000, 600000, 250000,
                                  12800000, 64000, 65536, 4000, 16384, 128,
                                  65536, 4000, 16384, 128};
  int map[15];
  bool posOK = (n_in >= 15);
  for (int i = 0; posOK && i < 15; ++i) posOK = (in_sizes[i] == exp_sz[i]);
  if (posOK) {
    for (int i = 0; i < 15; ++i) map[i] = i;
  } else {
    bool used[64] = {};
    for (int i = 0; i < 15; ++i) {
      map[i] = -1;
      for (int j = 0; j < n_in && j < 64; ++j)
        if (!used[j] && in_sizes[j] == exp_sz[i]) { map[i] = j; used[j] = true; break; }
      if (map[i] < 0) map[i] = (i < n_in) ? i : 0;
    }
  }
  const void* entity = d_in[map[0]];
  const void* edge_index = d_in[map[1]];
  const void* edge_type = d_in[map[2]];
  const void* edge_norm = d_in[map[3]];
  const void* table = d_in[map[5]];
  const void* rel_emb = d_in[map[6]];
  const void* basis[2] = {d_in[map[7]], d_in[map[11]]};
  const void* att[2] = {d_in[map[8]], d_in[map[12]]};
  const void* root[2] = {d_in[map[9]], d_in[map[13]]};
  const void* bias[2] = {d_in[map[10]], d_in[map[14]]};

  // ---- fixed ws layout ----
  char* ws = (char*)d_ws;
  size_t off = 0;
  auto grab = [&](size_t bytes) { size_t o = off; off = alignup(off + bytes); return o; };
  int* flags = (int*)(ws + grab(16));
  float* att_f[2] = {(float*)(ws + grab(4000 * 4)), (float*)(ws + grab(4000 * 4))};
  float* bias_f[2] = {(float*)(ws + grab(DIM * 4)), (float*)(ws + grab(DIM * 4))};
  u16* Wt[2] = {(u16*)(ws + grab(640 * 128 * 2)), (u16*)(ws + grab(640 * 128 * 2))};
  int* cnt = (int*)(ws + grab((size_t)NROWS * 4));
  int* cursor = (int*)(ws + grab((size_t)NROWS * 4));
  int* rowPtr = (int*)(ws + grab((size_t)(NROWS + 1) * 4));
  int* bsum = (int*)(ws + grab((size_t)SCAN_B * 4));
  int* bofs = (int*)(ws + grab((size_t)SCAN_B * 4));
  int2* csr8 = (int2*)(ws + grab((size_t)EDGES * 8));
  u16* hbf = (u16*)(ws + grab((size_t)NROWS * DIM * 2));
  u16* hbf2 = (u16*)(ws + grab((size_t)NROWS * DIM * 2));
  size_t fixedB = off;

  // ---- pick node-chunk count NC (Z fits L3 at NC=1; prefer fewest dispatches) ----
  static const int ncOrd[5] = {1, 2, 4, 8, 16};
  int NC = 16;
  for (int i = 0; i < 5; ++i) {
    int nc = ncOrd[i];
    size_t r = (NROWS + nc - 1) / nc;
    if (fixedB + alignup(r * 512 * 2) <= ws_size) { NC = nc; break; }
  }
  const int rpc = (NROWS + NC - 1) / NC;
  u16* Z = (u16*)(ws + grab((size_t)rpc * 512 * 2));

  // ---- prep ----
  hipMemsetAsync(flags, 0, 16, stream);
  hipMemsetAsync(cnt, 0, (size_t)NROWS * 4, stream);
  detect_kernel<<<64, 256, 0, stream>>>((const u16*)table, entity, edge_index,
                                        edge_type, flags);
  pgh_kernel<<<PB + GB + HB, 256, 0, stream>>>(
      flags, basis[0], root[0], Wt[0], basis[1], root[1], Wt[1],
      att[0], att[1], att_f[0], att_f[1],
      bias[0], bias[1], bias_f[0], bias_f[1],
      rel_emb, (float*)d_out + (size_t)NROWS * DIM,
      entity, table, hbf, edge_index, cnt);
  scan1_kernel<<<SCAN_B, 256, 0, stream>>>(cnt, rowPtr, bsum);
  scan2_kernel<<<1, 512, 0, stream>>>(bsum, bofs, rowPtr);
  scan3_kernel<<<SCAN_B, 256, 0, stream>>>(rowPtr, bofs, cursor);
  scatter_kernel<<<(EDGES + 255) / 256, 256, 0, stream>>>(
      flags, edge_index, edge_type, edge_norm, cursor, csr8);

  // ---- two RGCN layers: aggregate in input space, then one fused K=640 GEMM ----
  const u16* hin = hbf;
  for (int l = 0; l < 2; ++l) {
    for (int c = 0; c < NC; ++c) {
      int c0 = c * rpc, c1 = (c0 + rpc < NROWS) ? c0 + rpc : NROWS;
      int rc = c1 - c0;
      zagg_kernel<<<(rc * 64 + 255) / 256, 256, 0, stream>>>(
          rowPtr, csr8, att_f[l], hin, Z, c0, c1);
      fgemm_kernel<<<(rc + 63) / 64, 512, 0, stream>>>(
          Z, hin, Wt[l], bias_f[l], c0, c1, (l == 0) ? 1 : 2, hbf2, (float*)d_out);
    }
    hin = hbf2;
  }
}

// Round 15
// 418.157 us; speedup vs baseline: 1.0838x; 1.0002x over previous
//
#include <hip/hip_runtime.h>
#include <hip/hip_bf16.h>

#define NROWS 100000
#define EDGES 600000
#define DIM 128
#define SCAN_B 391   // ceil(100000/256)

typedef unsigned short u16;
typedef __attribute__((ext_vector_type(8))) short v8s;   // 8 bf16 (4 VGPRs)
typedef __attribute__((ext_vector_type(4))) float v4f;
typedef __attribute__((ext_vector_type(2))) float f2;    // packed fp32 (v_pk_*_f32)

static __device__ __forceinline__ float bf2f(u16 u) {
  union { unsigned u; float f; } c;
  c.u = (unsigned)u << 16;
  return c.f;
}
static __device__ __forceinline__ u16 f2bf(float f) {
  union { float f; unsigned u; } c;
  c.f = f;
  unsigned r = c.u + 0x7fff + ((c.u >> 16) & 1);   // RNE
  return (u16)(r >> 16);
}
// two bf16 (packed in a dword) -> f2 {lo, hi}
static __device__ __forceinline__ f2 bfpair(unsigned v) {
  union { unsigned u[2]; f2 f; } c;
  c.u[0] = v << 16;
  c.u[1] = v & 0xffff0000u;
  return c.f;
}
static __device__ __forceinline__ long ld_idx(const void* p, long i, int is64) {
  return is64 ? (long)((const long long*)p)[i] : (long)((const int*)p)[i];
}
static __device__ __forceinline__ float ld_f(const int* flags, const void* p, long i) {
  return flags[0] ? ((const float*)p)[i] : bf2f(((const u16*)p)[i]);
}

// flags (counts; pre-zeroed by memset):
//   flags[0] = # of 0xFF-exponent u16s in table  (>0 => table is fp32)
//   flags[1] = 1 if entity is i64 (direct write, single writer)
//   flags[2] = # of nonzero high-words in edge_index head (>0 => i32; ==0 => i64)
//   flags[3] = same for edge_type
__global__ __launch_bounds__(256) void detect_kernel(
    const u16* __restrict__ table, const void* __restrict__ entity,
    const void* __restrict__ ei, const void* __restrict__ et,
    int* __restrict__ flags) {
  int gid = blockIdx.x * 256 + threadIdx.x;       // 64 blocks = 16384 threads
  const ushort4* t4 = (const ushort4*)table;      // 65536 u16 = 16384 ushort4
  ushort4 v = t4[gid];
  int cf = ((((v.x >> 7) & 0xFF) == 0xFF) ? 1 : 0) +
           ((((v.y >> 7) & 0xFF) == 0xFF) ? 1 : 0) +
           ((((v.z >> 7) & 0xFF) == 0xFF) ? 1 : 0) +
           ((((v.w >> 7) & 0xFF) == 0xFF) ? 1 : 0);
  int cei = 0, cet = 0;
  if (gid < 1024) {
    cei = (((const int*)ei)[2 * gid + 1] != 0) ? 1 : 0;
    cet = (((const int*)et)[2 * gid + 1] != 0) ? 1 : 0;
  }
  __shared__ int s_f, s_ei, s_et;
  if (threadIdx.x == 0) { s_f = 0; s_ei = 0; s_et = 0; }
  __syncthreads();
  if (cf) atomicAdd(&s_f, cf);
  if (cei) atomicAdd(&s_ei, cei);
  if (cet) atomicAdd(&s_et, cet);
  __syncthreads();
  if (threadIdx.x == 0) {
    if (s_f) atomicAdd(flags + 0, s_f);
    if (s_ei) atomicAdd(flags + 2, s_ei);
    if (s_et) atomicAdd(flags + 3, s_et);
  }
  if (gid == 0) flags[1] = (((const int*)entity)[1] == 0) ? 1 : 0;
}

// -------- fused prep | gather | hist (all depend only on flags; disjoint outputs,
// complementary bottlenecks: streaming / gather-latency / atomic line-fill) ------
// Wt stored FRAGMENT-ORDERED per 128-row segment (32 KB blocks):
//   phys u16 index within seg = (k>>3)*1024 + col*8 + (k&7)
// Logical row n = seg*128+col: n<512 -> basis[b=n>>7][k][c=n&127]; else root[k][n-512].
#define PREP_THREADS (163840 + 64000 + 4000 + 4000 + 128 + 128)
#define PB ((PREP_THREADS + 255) / 256)        // 923
#define GB ((NROWS * 32 + 255) / 256)          // 12500
#define HB ((EDGES + 255) / 256)               // 2344
__global__ __launch_bounds__(256) void pgh_kernel(
    const int* __restrict__ flags,
    const void* __restrict__ basis0, const void* __restrict__ root0, u16* __restrict__ Wt0,
    const void* __restrict__ basis1, const void* __restrict__ root1, u16* __restrict__ Wt1,
    const void* __restrict__ att0, const void* __restrict__ att1,
    float* __restrict__ attf0, float* __restrict__ attf1,
    const void* __restrict__ bias0, const void* __restrict__ bias1,
    float* __restrict__ biasf0, float* __restrict__ biasf1,
    const void* __restrict__ rel, float* __restrict__ relout,
    const void* __restrict__ entity, const void* __restrict__ table,
    u16* __restrict__ hbf,
    const void* __restrict__ ei, int* __restrict__ cnt) {
  int b = blockIdx.x;
  if (b < PB) {
    // ---- prep ----
    int i = b * 256 + threadIdx.x;
    if (i < 2 * 81920) {
      const void* basis = (i < 81920) ? basis0 : basis1;
      const void* root = (i < 81920) ? root0 : root1;
      u16* Wt = (i < 81920) ? Wt0 : Wt1;
      int j = (i < 81920) ? i : i - 81920;
      int seg = j >> 14;            // 0..4 (16384 u16 per segment)
      int r = j & 16383;
      int kq = r >> 10;             // k>>3, 0..15
      int col = (r >> 3) & 127;
      int w = r & 7;
      int k = kq * 8 + w;
      int n = seg * 128 + col;
      float v;
      if (n < 512) {
        int bb = n >> 7, c = n & 127;
        v = ld_f(flags, basis, (long)bb * DIM * DIM + (long)k * DIM + c);
      } else {
        v = ld_f(flags, root, (long)k * DIM + (n - 512));
      }
      Wt[j] = f2bf(v);
      return;
    }
    i -= 163840;
    if (i < 64000) { relout[i] = ld_f(flags, rel, i); return; }
    i -= 64000;
    if (i < 4000) { attf0[i] = ld_f(flags, att0, i); return; }
    i -= 4000;
    if (i < 4000) { attf1[i] = ld_f(flags, att1, i); return; }
    i -= 4000;
    if (i < 128) { biasf0[i] = ld_f(flags, bias0, i); return; }
    i -= 128;
    if (i < 128) biasf1[i] = ld_f(flags, bias1, i);
    return;
  }
  if (b < PB + GB) {
    // ---- gather: hbf = bf16(table[entity[row]]) ----
    int gid = (b - PB) * 256 + threadIdx.x;      // N*32 threads, 4 elems each
    int row = gid >> 5, c4 = (gid & 31) * 4;
    if (row >= NROWS) return;
    long src = ld_idx(entity, row, flags[1]);
    ushort4 o;
    if (flags[0]) {
      float4 a = *(const float4*)((const float*)table + src * DIM + c4);
      o = make_ushort4(f2bf(a.x), f2bf(a.y), f2bf(a.z), f2bf(a.w));
    } else {
      o = *(const ushort4*)((const u16*)table + src * DIM + c4);
    }
    *(ushort4*)(hbf + (long)row * DIM + c4) = o;
    return;
  }
  // ---- hist ----
  int e = (b - PB - GB) * 256 + threadIdx.x;
  if (e < EDGES) atomicAdd(cnt + ld_idx(ei, EDGES + e, flags[2] == 0), 1);
}

// -------- CSR build -------------------------------------------------------------
__global__ __launch_bounds__(256) void scan1_kernel(const int* __restrict__ cnt,
                                                    int* __restrict__ rowPtr,
                                                    int* __restrict__ bsum) {
  __shared__ int sh[256];
  int i = blockIdx.x * 256 + threadIdx.x;
  int v = (i < NROWS) ? cnt[i] : 0;
  sh[threadIdx.x] = v;
  __syncthreads();
#pragma unroll
  for (int off = 1; off < 256; off <<= 1) {
    int t = (threadIdx.x >= off) ? sh[threadIdx.x - off] : 0;
    __syncthreads();
    sh[threadIdx.x] += t;
    __syncthreads();
  }
  if (i < NROWS) rowPtr[i] = sh[threadIdx.x] - v;
  if (threadIdx.x == 255) bsum[blockIdx.x] = sh[255];
}

__global__ __launch_bounds__(512) void scan2_kernel(int* __restrict__ bsum,
                                                    int* __restrict__ bofs,
                                                    int* __restrict__ rowPtr) {
  __shared__ int sh[512];
  int v = (threadIdx.x < SCAN_B) ? bsum[threadIdx.x] : 0;
  sh[threadIdx.x] = v;
  __syncthreads();
#pragma unroll
  for (int off = 1; off < 512; off <<= 1) {
    int t = (threadIdx.x >= off) ? sh[threadIdx.x - off] : 0;
    __syncthreads();
    sh[threadIdx.x] += t;
    __syncthreads();
  }
  if (threadIdx.x < SCAN_B) bofs[threadIdx.x] = sh[threadIdx.x] - v;
  if (threadIdx.x == 511) rowPtr[NROWS] = sh[511];
}

__global__ __launch_bounds__(256) void scan3_kernel(int* __restrict__ rowPtr,
                                                    const int* __restrict__ bofs,
                                                    int* __restrict__ cursor) {
  int i = blockIdx.x * 256 + threadIdx.x;
  if (i >= NROWS) return;
  int r = rowPtr[i] + bofs[blockIdx.x];
  rowPtr[i] = r;
  cursor[i] = r;
}

// One 8B store per edge: {src | t<<17, norm bits}.
__global__ __launch_bounds__(256) void scatter_kernel(const int* __restrict__ flags,
                                                      const void* __restrict__ ei,
                                                      const void* __restrict__ et,
                                                      const void* __restrict__ enorm,
                                                      int* __restrict__ cursor,
                                                      int2* __restrict__ csr8) {
  int e = blockIdx.x * 256 + threadIdx.x;
  if (e >= EDGES) return;
  int is64e = (flags[2] == 0), is64t = (flags[3] == 0);
  int dst = (int)ld_idx(ei, EDGES + e, is64e);
  int src = (int)ld_idx(ei, e, is64e);
  int t = (int)ld_idx(et, e, is64t);
  float nrm = ld_f(flags, enorm, e);
  int pos = atomicAdd(cursor + dst, 1);
  int2 v;
  v.x = src | (t << 17);
  v.y = __float_as_int(nrm);
  csr8[pos] = v;
}

// -------- input-space aggregation: Z_b[dst] = (1/deg) * sum_e att[t][b]*norm*h[src]
// One wave per dst node; lane covers cols {2*lane, 2*lane+1} as a PACKED float2.
// Edge loop unrolled x4. Gathers use 32-BIT BYTE OFFSETS against the uniform hin
// base (off = src<<8 | lane<<2, max 25.6MB): compiler emits SGPR-base + voffset
// loads, cutting the 64-bit per-gather address chains (~5 ops) to ~2 VALU ops.
__global__ __launch_bounds__(256) void zagg_kernel(
    const int* __restrict__ rowPtr, const int2* __restrict__ csr8,
    const float* __restrict__ att_f,
    const u16* __restrict__ hin, u16* __restrict__ Z, int c0, int c1) {
  int wid = (blockIdx.x * 256 + threadIdx.x) >> 6;
  int node = c0 + wid;
  if (node >= c1) return;
  int lane = threadIdx.x & 63;
  unsigned dby = (unsigned)(lane << 2);          // byte offset of this lane's pair
  const char* hb = (const char*)hin;
  int beg = rowPtr[node], end = rowPtr[node + 1];
  const float4* att4 = (const float4*)att_f;
  f2 z0 = {0.f, 0.f}, z1 = {0.f, 0.f}, z2 = {0.f, 0.f}, z3 = {0.f, 0.f};
  int e = beg;
  for (; e + 3 < end; e += 4) {
    int2 p0 = csr8[e], p1 = csr8[e + 1], p2 = csr8[e + 2], p3 = csr8[e + 3];
    unsigned v0 = *(const unsigned*)(hb + (((unsigned)(p0.x & 0x1FFFF) << 8) + dby));
    unsigned v1 = *(const unsigned*)(hb + (((unsigned)(p1.x & 0x1FFFF) << 8) + dby));
    unsigned v2 = *(const unsigned*)(hb + (((unsigned)(p2.x & 0x1FFFF) << 8) + dby));
    unsigned v3 = *(const unsigned*)(hb + (((unsigned)(p3.x & 0x1FFFF) << 8) + dby));
    float4 a0 = att4[p0.x >> 17];
    float4 a1 = att4[p1.x >> 17];
    float4 a2 = att4[p2.x >> 17];
    float4 a3 = att4[p3.x >> 17];
    float n0 = __int_as_float(p0.y), n1 = __int_as_float(p1.y);
    float n2 = __int_as_float(p2.y), n3 = __int_as_float(p3.y);
    f2 y0 = bfpair(v0) * (f2){n0, n0};
    f2 y1 = bfpair(v1) * (f2){n1, n1};
    f2 y2 = bfpair(v2) * (f2){n2, n2};
    f2 y3 = bfpair(v3) * (f2){n3, n3};
    z0 = (f2){a0.x, a0.x} * y0 + z0;
    z1 = (f2){a0.y, a0.y} * y0 + z1;
    z2 = (f2){a0.z, a0.z} * y0 + z2;
    z3 = (f2){a0.w, a0.w} * y0 + z3;
    z0 = (f2){a1.x, a1.x} * y1 + z0;
    z1 = (f2){a1.y, a1.y} * y1 + z1;
    z2 = (f2){a1.z, a1.z} * y1 + z2;
    z3 = (f2){a1.w, a1.w} * y1 + z3;
    z0 = (f2){a2.x, a2.x} * y2 + z0;
    z1 = (f2){a2.y, a2.y} * y2 + z1;
    z2 = (f2){a2.z, a2.z} * y2 + z2;
    z3 = (f2){a2.w, a2.w} * y2 + z3;
    z0 = (f2){a3.x, a3.x} * y3 + z0;
    z1 = (f2){a3.y, a3.y} * y3 + z1;
    z2 = (f2){a3.z, a3.z} * y3 + z2;
    z3 = (f2){a3.w, a3.w} * y3 + z3;
  }
  for (; e < end; ++e) {
    int2 p0 = csr8[e];
    unsigned v0 = *(const unsigned*)(hb + (((unsigned)(p0.x & 0x1FFFF) << 8) + dby));
    float4 a0 = att4[p0.x >> 17];
    float n0 = __int_as_float(p0.y);
    f2 y0 = bfpair(v0) * (f2){n0, n0};
    z0 = (f2){a0.x, a0.x} * y0 + z0;
    z1 = (f2){a0.y, a0.y} * y0 + z1;
    z2 = (f2){a0.z, a0.z} * y0 + z2;
    z3 = (f2){a0.w, a0.w} * y0 + z3;
  }
  float invd = 1.0f / fmaxf((float)(end - beg), 1.0f);
  f2 iv = {invd, invd};
  z0 *= iv; z1 *= iv; z2 *= iv; z3 *= iv;
  unsigned* zp = (unsigned*)(Z + (long)(node - c0) * 512) + lane;
  zp[0]   = (unsigned)f2bf(z0[0]) | ((unsigned)f2bf(z0[1]) << 16);
  zp[64]  = (unsigned)f2bf(z1[0]) | ((unsigned)f2bf(z1[1]) << 16);
  zp[128] = (unsigned)f2bf(z2[0]) | ((unsigned)f2bf(z2[1]) << 16);
  zp[192] = (unsigned)f2bf(z3[0]) | ((unsigned)f2bf(z3[1]) << 16);
}

// -------- fused GEMM over K=640: out = [Z0|Z1|Z2|Z3|h] @ Wt^T + bias ------------
// 512 threads, 64 rows/block, 8 waves = 4 row-frags x 2 col-halves.
// Wt fragment-ordered (see prep): staging = straight 32KB linear copy; each
// B-fragment ds_read_b128 is contiguous -> no bank conflicts (r12/r14-verified).
// NEW: A-fragment register double-buffer across segments — seg+1's 4 A-loads are
// issued right after the post-stage barrier, so their HBM/L3 latency hides under
// seg's 16 MFMAs instead of preceding them (r14 counters: MfmaUtil 10%, A-load
// latency exposed 5x per block).
// Segments 0..3: A from Z (chunk-local), segment 4: A from hin (root term).
// finalMode 1: hout = bf16(relu(out)) | 2: outp = fp32 out
__global__ __launch_bounds__(512) void fgemm_kernel(
    const u16* __restrict__ Z, const u16* __restrict__ hin,
    const u16* __restrict__ Wt, const float* __restrict__ bias,
    int c0, int c1, int finalMode,
    u16* __restrict__ hout, float* __restrict__ outp) {
  __shared__ u16 Wl[16384];   // 32 KB, fragment layout [k>>3][col][k&7]
  int tid = threadIdx.x;
  int wv = tid >> 6, lane = tid & 63;
  int rt = wv >> 1, ch = wv & 1;          // row-frag 0..3, col-half 0..1
  int quad = lane >> 4, l16 = lane & 15;
  long lrow = (long)blockIdx.x * 64 + rt * 16 + l16;   // chunk-local
  long arow = c0 + lrow;
  bool rv = arow < c1;

  v4f av[4];
#pragma unroll
  for (int nt = 0; nt < 4; ++nt) av[nt] = (v4f){0.f, 0.f, 0.f, 0.f};

  const v8s zv = {0, 0, 0, 0, 0, 0, 0, 0};
  v8s aC[4], aN[4];
  {
    const u16* ab = Z + lrow * 512;      // seg 0
#pragma unroll
    for (int ks = 0; ks < 4; ++ks) {
      aC[ks] = zv;
      if (rv) aC[ks] = *(const v8s*)&ab[ks * 32 + quad * 8];
    }
  }

#pragma unroll
  for (int seg = 0; seg < 5; ++seg) {
    if (seg) __syncthreads();            // protect Wl before overwrite
#pragma unroll
    for (int it = 0; it < 4; ++it) {
      int o = (tid + it * 512) * 8;
      *(int4*)&Wl[o] = *(const int4*)&Wt[(long)seg * 16384 + o];
    }
    __syncthreads();
    if (seg < 4) {                       // prefetch next segment's A
      const u16* abn = (seg < 3) ? Z + lrow * 512 + (seg + 1) * 128
                                 : hin + arow * 128;
#pragma unroll
      for (int ks = 0; ks < 4; ++ks) {
        aN[ks] = zv;
        if (rv) aN[ks] = *(const v8s*)&abn[ks * 32 + quad * 8];
      }
    }
#pragma unroll
    for (int ks = 0; ks < 4; ++ks) {
      const u16* wb = &Wl[(ks * 4 + quad) * 1024 + ch * 512];
#pragma unroll
      for (int nt = 0; nt < 4; ++nt) {
        v8s b = *(const v8s*)&wb[(nt * 16 + l16) * 8];
        av[nt] = __builtin_amdgcn_mfma_f32_16x16x32_bf16(aC[ks], b, av[nt], 0, 0, 0);
      }
    }
#pragma unroll
    for (int ks = 0; ks < 4; ++ks) aC[ks] = aN[ks];
  }

  long orow0 = c0 + (long)blockIdx.x * 64 + rt * 16 + quad * 4;
#pragma unroll
  for (int nt = 0; nt < 4; ++nt) {
    int col = ch * 64 + nt * 16 + l16;
    float bv = bias[col];
#pragma unroll
    for (int r = 0; r < 4; ++r) {
      long row = orow0 + r;
      if (row >= c1) continue;
      float v = av[nt][r] + bv;
      if (finalMode == 1) hout[row * DIM + col] = f2bf(fmaxf(v, 0.f));
      else                outp[row * DIM + col] = v;
    }
  }
}

static size_t alignup(size_t x) { return (x + 255) & ~(size_t)255; }

extern "C" void kernel_launch(void* const* d_in, const int* in_sizes, int n_in,
                              void* d_out, int out_size, void* d_ws, size_t ws_size,
                              hipStream_t stream) {
  static const long exp_sz[15] = {100000, 1200000, 600000, 600000, 250000,
                                  12800000, 64000, 65536, 4000, 16384, 128,
                                  65536, 4000, 16384, 128};
  int map[15];
  bool posOK = (n_in >= 15);
  for (int i = 0; posOK && i < 15; ++i) posOK = (in_sizes[i] == exp_sz[i]);
  if (posOK) {
    for (int i = 0; i < 15; ++i) map[i] = i;
  } else {
    bool used[64] = {};
    for (int i = 0; i < 15; ++i) {
      map[i] = -1;
      for (int j = 0; j < n_in && j < 64; ++j)
        if (!used[j] && in_sizes[j] == exp_sz[i]) { map[i] = j; used[j] = true; break; }
      if (map[i] < 0) map[i] = (i < n_in) ? i : 0;
    }
  }
  const void* entity = d_in[map[0]];
  const void* edge_index = d_in[map[1]];
  const void* edge_type = d_in[map[2]];
  const void* edge_norm = d_in[map[3]];
  const void* table = d_in[map[5]];
  const void* rel_emb = d_in[map[6]];
  const void* basis[2] = {d_in[map[7]], d_in[map[11]]};
  const void* att[2] = {d_in[map[8]], d_in[map[12]]};
  const void* root[2] = {d_in[map[9]], d_in[map[13]]};
  const void* bias[2] = {d_in[map[10]], d_in[map[14]]};

  // ---- fixed ws layout ----
  char* ws = (char*)d_ws;
  size_t off = 0;
  auto grab = [&](size_t bytes) { size_t o = off; off = alignup(off + bytes); return o; };
  int* flags = (int*)(ws + grab(16));
  float* att_f[2] = {(float*)(ws + grab(4000 * 4)), (float*)(ws + grab(4000 * 4))};
  float* bias_f[2] = {(float*)(ws + grab(DIM * 4)), (float*)(ws + grab(DIM * 4))};
  u16* Wt[2] = {(u16*)(ws + grab(640 * 128 * 2)), (u16*)(ws + grab(640 * 128 * 2))};
  int* cnt = (int*)(ws + grab((size_t)NROWS * 4));
  int* cursor = (int*)(ws + grab((size_t)NROWS * 4));
  int* rowPtr = (int*)(ws + grab((size_t)(NROWS + 1) * 4));
  int* bsum = (int*)(ws + grab((size_t)SCAN_B * 4));
  int* bofs = (int*)(ws + grab((size_t)SCAN_B * 4));
  int2* csr8 = (int2*)(ws + grab((size_t)EDGES * 8));
  u16* hbf = (u16*)(ws + grab((size_t)NROWS * DIM * 2));
  u16* hbf2 = (u16*)(ws + grab((size_t)NROWS * DIM * 2));
  size_t fixedB = off;

  // ---- pick node-chunk count NC (Z fits L3 at NC=1; prefer fewest dispatches) ----
  static const int ncOrd[5] = {1, 2, 4, 8, 16};
  int NC = 16;
  for (int i = 0; i < 5; ++i) {
    int nc = ncOrd[i];
    size_t r = (NROWS + nc - 1) / nc;
    if (fixedB + alignup(r * 512 * 2) <= ws_size) { NC = nc; break; }
  }
  const int rpc = (NROWS + NC - 1) / NC;
  u16* Z = (u16*)(ws + grab((size_t)rpc * 512 * 2));

  // ---- prep ----
  hipMemsetAsync(flags, 0, 16, stream);
  hipMemsetAsync(cnt, 0, (size_t)NROWS * 4, stream);
  detect_kernel<<<64, 256, 0, stream>>>((const u16*)table, entity, edge_index,
                                        edge_type, flags);
  pgh_kernel<<<PB + GB + HB, 256, 0, stream>>>(
      flags, basis[0], root[0], Wt[0], basis[1], root[1], Wt[1],
      att[0], att[1], att_f[0], att_f[1],
      bias[0], bias[1], bias_f[0], bias_f[1],
      rel_emb, (float*)d_out + (size_t)NROWS * DIM,
      entity, table, hbf, edge_index, cnt);
  scan1_kernel<<<SCAN_B, 256, 0, stream>>>(cnt, rowPtr, bsum);
  scan2_kernel<<<1, 512, 0, stream>>>(bsum, bofs, rowPtr);
  scan3_kernel<<<SCAN_B, 256, 0, stream>>>(rowPtr, bofs, cursor);
  scatter_kernel<<<(EDGES + 255) / 256, 256, 0, stream>>>(
      flags, edge_index, edge_type, edge_norm, cursor, csr8);

  // ---- two RGCN layers: aggregate in input space, then one fused K=640 GEMM ----
  const u16* hin = hbf;
  for (int l = 0; l < 2; ++l) {
    for (int c = 0; c < NC; ++c) {
      int c0 = c * rpc, c1 = (c0 + rpc < NROWS) ? c0 + rpc : NROWS;
      int rc = c1 - c0;
      zagg_kernel<<<(rc * 64 + 255) / 256, 256, 0, stream>>>(
          rowPtr, csr8, att_f[l], hin, Z, c0, c1);
      fgemm_kernel<<<(rc + 63) / 64, 512, 0, stream>>>(
          Z, hin, Wt[l], bias_f[l], c0, c1, (l == 0) ? 1 : 2, hbf2, (float*)d_out);
    }
    hin = hbf2;
  }
}

// Round 16
// 408.633 us; speedup vs baseline: 1.1091x; 1.0233x over previous
//
#include <hip/hip_runtime.h>
#include <hip/hip_bf16.h>

#define NROWS 100000
#define EDGES 600000
#define DIM 128
#define SCAN_B 391   // ceil(100000/256)

typedef unsigned short u16;
typedef __attribute__((ext_vector_type(8))) short v8s;   // 8 bf16 (4 VGPRs)
typedef __attribute__((ext_vector_type(4))) float v4f;
typedef __attribute__((ext_vector_type(2))) float f2;    // packed fp32 (v_pk_*_f32)

static __device__ __forceinline__ float bf2f(u16 u) {
  union { unsigned u; float f; } c;
  c.u = (unsigned)u << 16;
  return c.f;
}
static __device__ __forceinline__ u16 f2bf(float f) {
  union { float f; unsigned u; } c;
  c.f = f;
  unsigned r = c.u + 0x7fff + ((c.u >> 16) & 1);   // RNE
  return (u16)(r >> 16);
}
// two bf16 (packed in a dword) -> f2 {lo, hi}
static __device__ __forceinline__ f2 bfpair(unsigned v) {
  union { unsigned u[2]; f2 f; } c;
  c.u[0] = v << 16;
  c.u[1] = v & 0xffff0000u;
  return c.f;
}
static __device__ __forceinline__ long ld_idx(const void* p, long i, int is64) {
  return is64 ? (long)((const long long*)p)[i] : (long)((const int*)p)[i];
}
static __device__ __forceinline__ float ld_f(const int* flags, const void* p, long i) {
  return flags[0] ? ((const float*)p)[i] : bf2f(((const u16*)p)[i]);
}

// flags (counts; pre-zeroed by memset):
//   flags[0] = # of 0xFF-exponent u16s in table  (>0 => table is fp32)
//   flags[1] = 1 if entity is i64 (direct write, single writer)
//   flags[2] = # of nonzero high-words in edge_index head (>0 => i32; ==0 => i64)
//   flags[3] = same for edge_type
__global__ __launch_bounds__(256) void detect_kernel(
    const u16* __restrict__ table, const void* __restrict__ entity,
    const void* __restrict__ ei, const void* __restrict__ et,
    int* __restrict__ flags) {
  int gid = blockIdx.x * 256 + threadIdx.x;       // 64 blocks = 16384 threads
  const ushort4* t4 = (const ushort4*)table;      // 65536 u16 = 16384 ushort4
  ushort4 v = t4[gid];
  int cf = ((((v.x >> 7) & 0xFF) == 0xFF) ? 1 : 0) +
           ((((v.y >> 7) & 0xFF) == 0xFF) ? 1 : 0) +
           ((((v.z >> 7) & 0xFF) == 0xFF) ? 1 : 0) +
           ((((v.w >> 7) & 0xFF) == 0xFF) ? 1 : 0);
  int cei = 0, cet = 0;
  if (gid < 1024) {
    cei = (((const int*)ei)[2 * gid + 1] != 0) ? 1 : 0;
    cet = (((const int*)et)[2 * gid + 1] != 0) ? 1 : 0;
  }
  __shared__ int s_f, s_ei, s_et;
  if (threadIdx.x == 0) { s_f = 0; s_ei = 0; s_et = 0; }
  __syncthreads();
  if (cf) atomicAdd(&s_f, cf);
  if (cei) atomicAdd(&s_ei, cei);
  if (cet) atomicAdd(&s_et, cet);
  __syncthreads();
  if (threadIdx.x == 0) {
    if (s_f) atomicAdd(flags + 0, s_f);
    if (s_ei) atomicAdd(flags + 2, s_ei);
    if (s_et) atomicAdd(flags + 3, s_et);
  }
  if (gid == 0) flags[1] = (((const int*)entity)[1] == 0) ? 1 : 0;
}

// -------- fused prep | gather | hist (all depend only on flags; disjoint outputs,
// complementary bottlenecks: streaming / gather-latency / atomic line-fill) ------
// Wt stored FRAGMENT-ORDERED per 128-row segment (32 KB blocks):
//   phys u16 index within seg = (k>>3)*1024 + col*8 + (k&7)
// Logical row n = seg*128+col: n<512 -> basis[b=n>>7][k][c=n&127]; else root[k][n-512].
#define PREP_THREADS (163840 + 64000 + 4000 + 4000 + 128 + 128)
#define PB ((PREP_THREADS + 255) / 256)        // 923
#define GB ((NROWS * 32 + 255) / 256)          // 12500
#define HB ((EDGES + 255) / 256)               // 2344
__global__ __launch_bounds__(256) void pgh_kernel(
    const int* __restrict__ flags,
    const void* __restrict__ basis0, const void* __restrict__ root0, u16* __restrict__ Wt0,
    const void* __restrict__ basis1, const void* __restrict__ root1, u16* __restrict__ Wt1,
    const void* __restrict__ att0, const void* __restrict__ att1,
    float* __restrict__ attf0, float* __restrict__ attf1,
    const void* __restrict__ bias0, const void* __restrict__ bias1,
    float* __restrict__ biasf0, float* __restrict__ biasf1,
    const void* __restrict__ rel, float* __restrict__ relout,
    const void* __restrict__ entity, const void* __restrict__ table,
    u16* __restrict__ hbf,
    const void* __restrict__ ei, int* __restrict__ cnt) {
  int b = blockIdx.x;
  if (b < PB) {
    // ---- prep ----
    int i = b * 256 + threadIdx.x;
    if (i < 2 * 81920) {
      const void* basis = (i < 81920) ? basis0 : basis1;
      const void* root = (i < 81920) ? root0 : root1;
      u16* Wt = (i < 81920) ? Wt0 : Wt1;
      int j = (i < 81920) ? i : i - 81920;
      int seg = j >> 14;            // 0..4 (16384 u16 per segment)
      int r = j & 16383;
      int kq = r >> 10;             // k>>3, 0..15
      int col = (r >> 3) & 127;
      int w = r & 7;
      int k = kq * 8 + w;
      int n = seg * 128 + col;
      float v;
      if (n < 512) {
        int bb = n >> 7, c = n & 127;
        v = ld_f(flags, basis, (long)bb * DIM * DIM + (long)k * DIM + c);
      } else {
        v = ld_f(flags, root, (long)k * DIM + (n - 512));
      }
      Wt[j] = f2bf(v);
      return;
    }
    i -= 163840;
    if (i < 64000) { relout[i] = ld_f(flags, rel, i); return; }
    i -= 64000;
    if (i < 4000) { attf0[i] = ld_f(flags, att0, i); return; }
    i -= 4000;
    if (i < 4000) { attf1[i] = ld_f(flags, att1, i); return; }
    i -= 4000;
    if (i < 128) { biasf0[i] = ld_f(flags, bias0, i); return; }
    i -= 128;
    if (i < 128) biasf1[i] = ld_f(flags, bias1, i);
    return;
  }
  if (b < PB + GB) {
    // ---- gather: hbf = bf16(table[entity[row]]) ----
    int gid = (b - PB) * 256 + threadIdx.x;      // N*32 threads, 4 elems each
    int row = gid >> 5, c4 = (gid & 31) * 4;
    if (row >= NROWS) return;
    long src = ld_idx(entity, row, flags[1]);
    ushort4 o;
    if (flags[0]) {
      float4 a = *(const float4*)((const float*)table + src * DIM + c4);
      o = make_ushort4(f2bf(a.x), f2bf(a.y), f2bf(a.z), f2bf(a.w));
    } else {
      o = *(const ushort4*)((const u16*)table + src * DIM + c4);
    }
    *(ushort4*)(hbf + (long)row * DIM + c4) = o;
    return;
  }
  // ---- hist ----
  int e = (b - PB - GB) * 256 + threadIdx.x;
  if (e < EDGES) atomicAdd(cnt + ld_idx(ei, EDGES + e, flags[2] == 0), 1);
}

// -------- CSR build -------------------------------------------------------------
__global__ __launch_bounds__(256) void scan1_kernel(const int* __restrict__ cnt,
                                                    int* __restrict__ rowPtr,
                                                    int* __restrict__ bsum) {
  __shared__ int sh[256];
  int i = blockIdx.x * 256 + threadIdx.x;
  int v = (i < NROWS) ? cnt[i] : 0;
  sh[threadIdx.x] = v;
  __syncthreads();
#pragma unroll
  for (int off = 1; off < 256; off <<= 1) {
    int t = (threadIdx.x >= off) ? sh[threadIdx.x - off] : 0;
    __syncthreads();
    sh[threadIdx.x] += t;
    __syncthreads();
  }
  if (i < NROWS) rowPtr[i] = sh[threadIdx.x] - v;
  if (threadIdx.x == 255) bsum[blockIdx.x] = sh[255];
}

__global__ __launch_bounds__(512) void scan2_kernel(int* __restrict__ bsum,
                                                    int* __restrict__ bofs,
                                                    int* __restrict__ rowPtr) {
  __shared__ int sh[512];
  int v = (threadIdx.x < SCAN_B) ? bsum[threadIdx.x] : 0;
  sh[threadIdx.x] = v;
  __syncthreads();
#pragma unroll
  for (int off = 1; off < 512; off <<= 1) {
    int t = (threadIdx.x >= off) ? sh[threadIdx.x - off] : 0;
    __syncthreads();
    sh[threadIdx.x] += t;
    __syncthreads();
  }
  if (threadIdx.x < SCAN_B) bofs[threadIdx.x] = sh[threadIdx.x] - v;
  if (threadIdx.x == 511) rowPtr[NROWS] = sh[511];
}

__global__ __launch_bounds__(256) void scan3_kernel(int* __restrict__ rowPtr,
                                                    const int* __restrict__ bofs,
                                                    int* __restrict__ cursor) {
  int i = blockIdx.x * 256 + threadIdx.x;
  if (i >= NROWS) return;
  int r = rowPtr[i] + bofs[blockIdx.x];
  rowPtr[i] = r;
  cursor[i] = r;
}

// One 8B store per edge: {src | t<<17, norm bits}.
__global__ __launch_bounds__(256) void scatter_kernel(const int* __restrict__ flags,
                                                      const void* __restrict__ ei,
                                                      const void* __restrict__ et,
                                                      const void* __restrict__ enorm,
                                                      int* __restrict__ cursor,
                                                      int2* __restrict__ csr8) {
  int e = blockIdx.x * 256 + threadIdx.x;
  if (e >= EDGES) return;
  int is64e = (flags[2] == 0), is64t = (flags[3] == 0);
  int dst = (int)ld_idx(ei, EDGES + e, is64e);
  int src = (int)ld_idx(ei, e, is64e);
  int t = (int)ld_idx(et, e, is64t);
  float nrm = ld_f(flags, enorm, e);
  int pos = atomicAdd(cursor + dst, 1);
  int2 v;
  v.x = src | (t << 17);
  v.y = __float_as_int(nrm);
  csr8[pos] = v;
}

// -------- input-space aggregation: Z_b[dst] = (1/deg) * sum_e att[t][b]*norm*h[src]
// One wave per dst node; lane covers cols {2*lane, 2*lane+1} as a PACKED float2.
// Edge loop unrolled x4. Gathers use 32-BIT BYTE OFFSETS against the uniform hin
// base (off = src<<8 | lane<<2, max 25.6MB): compiler emits SGPR-base + voffset
// loads, cutting the 64-bit per-gather address chains (~5 ops) to ~2 VALU ops.
__global__ __launch_bounds__(256) void zagg_kernel(
    const int* __restrict__ rowPtr, const int2* __restrict__ csr8,
    const float* __restrict__ att_f,
    const u16* __restrict__ hin, u16* __restrict__ Z, int c0, int c1) {
  int wid = (blockIdx.x * 256 + threadIdx.x) >> 6;
  int node = c0 + wid;
  if (node >= c1) return;
  int lane = threadIdx.x & 63;
  unsigned dby = (unsigned)(lane << 2);          // byte offset of this lane's pair
  const char* hb = (const char*)hin;
  int beg = rowPtr[node], end = rowPtr[node + 1];
  const float4* att4 = (const float4*)att_f;
  f2 z0 = {0.f, 0.f}, z1 = {0.f, 0.f}, z2 = {0.f, 0.f}, z3 = {0.f, 0.f};
  int e = beg;
  for (; e + 3 < end; e += 4) {
    int2 p0 = csr8[e], p1 = csr8[e + 1], p2 = csr8[e + 2], p3 = csr8[e + 3];
    unsigned v0 = *(const unsigned*)(hb + (((unsigned)(p0.x & 0x1FFFF) << 8) + dby));
    unsigned v1 = *(const unsigned*)(hb + (((unsigned)(p1.x & 0x1FFFF) << 8) + dby));
    unsigned v2 = *(const unsigned*)(hb + (((unsigned)(p2.x & 0x1FFFF) << 8) + dby));
    unsigned v3 = *(const unsigned*)(hb + (((unsigned)(p3.x & 0x1FFFF) << 8) + dby));
    float4 a0 = att4[p0.x >> 17];
    float4 a1 = att4[p1.x >> 17];
    float4 a2 = att4[p2.x >> 17];
    float4 a3 = att4[p3.x >> 17];
    float n0 = __int_as_float(p0.y), n1 = __int_as_float(p1.y);
    float n2 = __int_as_float(p2.y), n3 = __int_as_float(p3.y);
    f2 y0 = bfpair(v0) * (f2){n0, n0};
    f2 y1 = bfpair(v1) * (f2){n1, n1};
    f2 y2 = bfpair(v2) * (f2){n2, n2};
    f2 y3 = bfpair(v3) * (f2){n3, n3};
    z0 = (f2){a0.x, a0.x} * y0 + z0;
    z1 = (f2){a0.y, a0.y} * y0 + z1;
    z2 = (f2){a0.z, a0.z} * y0 + z2;
    z3 = (f2){a0.w, a0.w} * y0 + z3;
    z0 = (f2){a1.x, a1.x} * y1 + z0;
    z1 = (f2){a1.y, a1.y} * y1 + z1;
    z2 = (f2){a1.z, a1.z} * y1 + z2;
    z3 = (f2){a1.w, a1.w} * y1 + z3;
    z0 = (f2){a2.x, a2.x} * y2 + z0;
    z1 = (f2){a2.y, a2.y} * y2 + z1;
    z2 = (f2){a2.z, a2.z} * y2 + z2;
    z3 = (f2){a2.w, a2.w} * y2 + z3;
    z0 = (f2){a3.x, a3.x} * y3 + z0;
    z1 = (f2){a3.y, a3.y} * y3 + z1;
    z2 = (f2){a3.z, a3.z} * y3 + z2;
    z3 = (f2){a3.w, a3.w} * y3 + z3;
  }
  for (; e < end; ++e) {
    int2 p0 = csr8[e];
    unsigned v0 = *(const unsigned*)(hb + (((unsigned)(p0.x & 0x1FFFF) << 8) + dby));
    float4 a0 = att4[p0.x >> 17];
    float n0 = __int_as_float(p0.y);
    f2 y0 = bfpair(v0) * (f2){n0, n0};
    z0 = (f2){a0.x, a0.x} * y0 + z0;
    z1 = (f2){a0.y, a0.y} * y0 + z1;
    z2 = (f2){a0.z, a0.z} * y0 + z2;
    z3 = (f2){a0.w, a0.w} * y0 + z3;
  }
  float invd = 1.0f / fmaxf((float)(end - beg), 1.0f);
  f2 iv = {invd, invd};
  z0 *= iv; z1 *= iv; z2 *= iv; z3 *= iv;
  unsigned* zp = (unsigned*)(Z + (long)(node - c0) * 512) + lane;
  zp[0]   = (unsigned)f2bf(z0[0]) | ((unsigned)f2bf(z0[1]) << 16);
  zp[64]  = (unsigned)f2bf(z1[0]) | ((unsigned)f2bf(z1[1]) << 16);
  zp[128] = (unsigned)f2bf(z2[0]) | ((unsigned)f2bf(z2[1]) << 16);
  zp[192] = (unsigned)f2bf(z3[0]) | ((unsigned)f2bf(z3[1]) << 16);
}

// -------- fused GEMM over K=640: out = [Z0|Z1|Z2|Z3|h] @ Wt^T + bias ------------
// 512 threads, 128 rows/block, 8 waves = 8 row-frags x FULL 128 cols each.
// Doubles MFMA per barrier/stage vs the 64-row version (32 MFMAs/seg/wave):
// staging traffic and barrier count per output row halve; all 8 waves
// broadcast-share the same Wl fragments. Wt fragment-ordered (see prep) ->
// staging is a straight 32KB linear copy, B ds_read_b128 conflict-free
// (r12/r14: SQ_LDS_BANK_CONFLICT = 0). No A-prefetch (r15: cost VGPRs, -occ).
// Segments 0..3: A from Z (chunk-local), segment 4: A from hin (root term).
// finalMode 1: hout = bf16(relu(out)) | 2: outp = fp32 out
__global__ __launch_bounds__(512) void fgemm_kernel(
    const u16* __restrict__ Z, const u16* __restrict__ hin,
    const u16* __restrict__ Wt, const float* __restrict__ bias,
    int c0, int c1, int finalMode,
    u16* __restrict__ hout, float* __restrict__ outp) {
  __shared__ u16 Wl[16384];   // 32 KB, fragment layout [k>>3][col][k&7]
  int tid = threadIdx.x;
  int wv = tid >> 6, lane = tid & 63;
  int quad = lane >> 4, l16 = lane & 15;
  long lrow = (long)blockIdx.x * 128 + wv * 16 + l16;   // chunk-local
  long arow = c0 + lrow;
  bool rv = arow < c1;

  v4f av[8];
#pragma unroll
  for (int nt = 0; nt < 8; ++nt) av[nt] = (v4f){0.f, 0.f, 0.f, 0.f};

  for (int seg = 0; seg < 5; ++seg) {
    if (seg) __syncthreads();            // protect Wl before overwrite
#pragma unroll
    for (int it = 0; it < 4; ++it) {
      int o = (tid + it * 512) * 8;
      *(int4*)&Wl[o] = *(const int4*)&Wt[(long)seg * 16384 + o];
    }
    __syncthreads();
    const u16* abase = (seg < 4) ? Z + lrow * 512 + seg * 128
                                 : hin + arow * 128;
#pragma unroll
    for (int ks = 0; ks < 4; ++ks) {
      v8s a = {0, 0, 0, 0, 0, 0, 0, 0};
      if (rv) a = *(const v8s*)&abase[ks * 32 + quad * 8];
      const u16* wb = &Wl[(ks * 4 + quad) * 1024];
#pragma unroll
      for (int nt = 0; nt < 8; ++nt) {
        v8s b = *(const v8s*)&wb[(nt * 16 + l16) * 8];
        av[nt] = __builtin_amdgcn_mfma_f32_16x16x32_bf16(a, b, av[nt], 0, 0, 0);
      }
    }
  }

  long orow0 = c0 + (long)blockIdx.x * 128 + wv * 16 + quad * 4;
#pragma unroll
  for (int nt = 0; nt < 8; ++nt) {
    int col = nt * 16 + l16;
    float bv = bias[col];
#pragma unroll
    for (int r = 0; r < 4; ++r) {
      long row = orow0 + r;
      if (row >= c1) continue;
      float v = av[nt][r] + bv;
      if (finalMode == 1) hout[row * DIM + col] = f2bf(fmaxf(v, 0.f));
      else                outp[row * DIM + col] = v;
    }
  }
}

static size_t alignup(size_t x) { return (x + 255) & ~(size_t)255; }

extern "C" void kernel_launch(void* const* d_in, const int* in_sizes, int n_in,
                              void* d_out, int out_size, void* d_ws, size_t ws_size,
                              hipStream_t stream) {
  static const long exp_sz[15] = {100000, 1200000, 600000, 600000, 250000,
                                  12800000, 64000, 65536, 4000, 16384, 128,
                                  65536, 4000, 16384, 128};
  int map[15];
  bool posOK = (n_in >= 15);
  for (int i = 0; posOK && i < 15; ++i) posOK = (in_sizes[i] == exp_sz[i]);
  if (posOK) {
    for (int i = 0; i < 15; ++i) map[i] = i;
  } else {
    bool used[64] = {};
    for (int i = 0; i < 15; ++i) {
      map[i] = -1;
      for (int j = 0; j < n_in && j < 64; ++j)
        if (!used[j] && in_sizes[j] == exp_sz[i]) { map[i] = j; used[j] = true; break; }
      if (map[i] < 0) map[i] = (i < n_in) ? i : 0;
    }
  }
  const void* entity = d_in[map[0]];
  const void* edge_index = d_in[map[1]];
  const void* edge_type = d_in[map[2]];
  const void* edge_norm = d_in[map[3]];
  const void* table = d_in[map[5]];
  const void* rel_emb = d_in[map[6]];
  const void* basis[2] = {d_in[map[7]], d_in[map[11]]};
  const void* att[2] = {d_in[map[8]], d_in[map[12]]};
  const void* root[2] = {d_in[map[9]], d_in[map[13]]};
  const void* bias[2] = {d_in[map[10]], d_in[map[14]]};

  // ---- fixed ws layout ----
  char* ws = (char*)d_ws;
  size_t off = 0;
  auto grab = [&](size_t bytes) { size_t o = off; off = alignup(off + bytes); return o; };
  int* flags = (int*)(ws + grab(16));
  float* att_f[2] = {(float*)(ws + grab(4000 * 4)), (float*)(ws + grab(4000 * 4))};
  float* bias_f[2] = {(float*)(ws + grab(DIM * 4)), (float*)(ws + grab(DIM * 4))};
  u16* Wt[2] = {(u16*)(ws + grab(640 * 128 * 2)), (u16*)(ws + grab(640 * 128 * 2))};
  int* cnt = (int*)(ws + grab((size_t)NROWS * 4));
  int* cursor = (int*)(ws + grab((size_t)NROWS * 4));
  int* rowPtr = (int*)(ws + grab((size_t)(NROWS + 1) * 4));
  int* bsum = (int*)(ws + grab((size_t)SCAN_B * 4));
  int* bofs = (int*)(ws + grab((size_t)SCAN_B * 4));
  int2* csr8 = (int2*)(ws + grab((size_t)EDGES * 8));
  u16* hbf = (u16*)(ws + grab((size_t)NROWS * DIM * 2));
  u16* hbf2 = (u16*)(ws + grab((size_t)NROWS * DIM * 2));
  size_t fixedB = off;

  // ---- pick node-chunk count NC (Z fits L3 at NC=1; prefer fewest dispatches) ----
  static const int ncOrd[5] = {1, 2, 4, 8, 16};
  int NC = 16;
  for (int i = 0; i < 5; ++i) {
    int nc = ncOrd[i];
    size_t r = (NROWS + nc - 1) / nc;
    if (fixedB + alignup(r * 512 * 2) <= ws_size) { NC = nc; break; }
  }
  const int rpc = (NROWS + NC - 1) / NC;
  u16* Z = (u16*)(ws + grab((size_t)rpc * 512 * 2));

  // ---- prep ----
  hipMemsetAsync(flags, 0, 16, stream);
  hipMemsetAsync(cnt, 0, (size_t)NROWS * 4, stream);
  detect_kernel<<<64, 256, 0, stream>>>((const u16*)table, entity, edge_index,
                                        edge_type, flags);
  pgh_kernel<<<PB + GB + HB, 256, 0, stream>>>(
      flags, basis[0], root[0], Wt[0], basis[1], root[1], Wt[1],
      att[0], att[1], att_f[0], att_f[1],
      bias[0], bias[1], bias_f[0], bias_f[1],
      rel_emb, (float*)d_out + (size_t)NROWS * DIM,
      entity, table, hbf, edge_index, cnt);
  scan1_kernel<<<SCAN_B, 256, 0, stream>>>(cnt, rowPtr, bsum);
  scan2_kernel<<<1, 512, 0, stream>>>(bsum, bofs, rowPtr);
  scan3_kernel<<<SCAN_B, 256, 0, stream>>>(rowPtr, bofs, cursor);
  scatter_kernel<<<(EDGES + 255) / 256, 256, 0, stream>>>(
      flags, edge_index, edge_type, edge_norm, cursor, csr8);

  // ---- two RGCN layers: aggregate in input space, then one fused K=640 GEMM ----
  const u16* hin = hbf;
  for (int l = 0; l < 2; ++l) {
    for (int c = 0; c < NC; ++c) {
      int c0 = c * rpc, c1 = (c0 + rpc < NROWS) ? c0 + rpc : NROWS;
      int rc = c1 - c0;
      zagg_kernel<<<(rc * 64 + 255) / 256, 256, 0, stream>>>(
          rowPtr, csr8, att_f[l], hin, Z, c0, c1);
      fgemm_kernel<<<(rc + 127) / 128, 512, 0, stream>>>(
          Z, hin, Wt[l], bias_f[l], c0, c1, (l == 0) ? 1 : 2, hbf2, (float*)d_out);
    }
    hin = hbf2;
  }
}